// Round 2
// baseline (1147.593 us; speedup 1.0000x reference)
//
#include <hip/hip_runtime.h>
#include <hip/hip_bf16.h>

typedef unsigned short u16;
typedef short bf16x8 __attribute__((ext_vector_type(8)));
typedef float f32x4 __attribute__((ext_vector_type(4)));

#define NN 100000
#define EE 3200000
static constexpr float COEF = 0.17677669529663687f; // 1/sqrt(32)

__device__ __forceinline__ float b2f(u16 u) { return __uint_as_float(((unsigned)u) << 16); }
__device__ __forceinline__ u16 f2b(float f) {
    unsigned u = __float_as_uint(f);
    unsigned r = (u + 0x7fffu + ((u >> 16) & 1u)) >> 16;
    return (u16)r;
}

#define GLDS16(gp, lp) __builtin_amdgcn_global_load_lds( \
    (const __attribute__((address_space(1))) void*)(gp), \
    (__attribute__((address_space(3))) void*)(lp), 16, 0, 0)

// ---------- conversions ----------
__global__ __launch_bounds__(256) void cvt_x_kernel(const float* __restrict__ in,
                                                    u16* __restrict__ out, int n4) {
    int i = blockIdx.x * 256 + threadIdx.x;
    if (i >= n4) return;
    float4 v = ((const float4*)in)[i];
    ushort4 o;
    o.x = f2b(v.x); o.y = f2b(v.y); o.z = f2b(v.z); o.w = f2b(v.w);
    ((ushort4*)out)[i] = o;
}

__global__ __launch_bounds__(256) void transpose_bf16_kernel(const float* __restrict__ in,
                                                             u16* __restrict__ out, int R, int C) {
    int idx = blockIdx.x * 256 + threadIdx.x;
    if (idx >= R * C) return;
    int r = idx / C, c = idx - r * C;
    out[(size_t)c * R + r] = f2b(in[idx]);
}

// ---------- CSR build ----------
__global__ __launch_bounds__(256) void hist_kernel(const int* __restrict__ dst,
                                                   int* __restrict__ deg) {
    int e = blockIdx.x * 256 + threadIdx.x;
    atomicAdd(&deg[dst[e]], 1);
}

__global__ __launch_bounds__(1024) void scan_kernel(const int* __restrict__ deg,
                                                    int* __restrict__ rowstart, int n) {
    __shared__ int sums[1024];
    int tid = threadIdx.x;
    int per = (n + 1023) >> 10;
    int lo = tid * per;
    int hi = lo + per; if (hi > n) hi = n; if (lo > n) lo = n;
    int s = 0;
    for (int i = lo; i < hi; ++i) s += deg[i];
    sums[tid] = s;
    __syncthreads();
    for (int off = 1; off < 1024; off <<= 1) {
        int v = (tid >= off) ? sums[tid - off] : 0;
        __syncthreads();
        sums[tid] += v;
        __syncthreads();
    }
    int run = (tid == 0) ? 0 : sums[tid - 1];
    for (int i = lo; i < hi; ++i) { rowstart[i] = run; run += deg[i]; }
    if (tid == 1023) rowstart[n] = sums[1023];
}

__global__ __launch_bounds__(256) void scatter_kernel(const int* __restrict__ src,
                                                      const int* __restrict__ dst,
                                                      const int* __restrict__ rowstart,
                                                      int* __restrict__ cursor,
                                                      int* __restrict__ esrc) {
    int e = blockIdx.x * 256 + threadIdx.x;
    int d = dst[e];
    int pos = atomicAdd(&cursor[d], 1);
    esrc[rowstart[d] + pos] = src[e];
}

// ---------- per-node attention: 1 wave per node, single-pass online softmax ----------
// lane = h*8 + i ; lane owns dims [h*32 + i*4, +4)
// NOTE: Q and msg may ALIAS (Q[node] is fully read into registers before msg[node]
// is written; each node touched by exactly one wave) -> no __restrict__ on them.
__global__ __launch_bounds__(256) void attn_kernel(
    const u16* Q, const u16* __restrict__ K, const u16* __restrict__ V,
    const int* __restrict__ rowstart, const int* __restrict__ esrc,
    u16* msg) {
    int node = blockIdx.x * 4 + (threadIdx.x >> 6);
    int lane = threadIdx.x & 63;
    int r0 = rowstart[node], r1 = rowstart[node + 1];

    float q0, q1, q2, q3;
    {
        ushort4 qa = *(const ushort4*)(Q + (size_t)node * 256 + lane * 4);
        q0 = b2f(qa.x); q1 = b2f(qa.y); q2 = b2f(qa.z); q3 = b2f(qa.w);
    }

    float m = -3.4e38f, denom = 0.0f;
    float a0 = 0, a1 = 0, a2 = 0, a3 = 0;
    for (int j = r0; j < r1; ++j) {
        int s = esrc[j];
        ushort4 ka = *(const ushort4*)(K + (size_t)s * 256 + lane * 4);
        ushort4 va = *(const ushort4*)(V + (size_t)s * 256 + lane * 4);
        float d = q0 * b2f(ka.x) + q1 * b2f(ka.y) + q2 * b2f(ka.z) + q3 * b2f(ka.w);
        d += __shfl_xor(d, 1);
        d += __shfl_xor(d, 2);
        d += __shfl_xor(d, 4);
        d *= COEF;
        float mn = fmaxf(m, d);          // uniform across the 8-lane head group
        float scale = __expf(m - mn);    // ==1 when max unchanged; ==0 on first edge
        float ex = __expf(d - mn);
        m = mn;
        denom = denom * scale + ex;
        a0 = a0 * scale + ex * b2f(va.x);
        a1 = a1 * scale + ex * b2f(va.y);
        a2 = a2 * scale + ex * b2f(va.z);
        a3 = a3 * scale + ex * b2f(va.w);
    }
    float inv = 1.0f / fmaxf(denom, 1e-20f);
    ushort4 o;
    o.x = f2b(a0 * inv); o.y = f2b(a1 * inv); o.z = f2b(a2 * inv); o.w = f2b(a3 * inv);
    *(ushort4*)(msg + (size_t)node * 256 + lane * 4) = o;
}

// ---------- bf16 MFMA GEMM: C(M x Ntot) = A(M x Ktot) * Bt(Ntot x Ktot)^T + bias ----------
// MODE 0: fp32 output, plain.  MODE 1: bf16 output de-interleaved into Q/K/V.
// A split: k < splitK reads A, else A2 (both row-stride 256) -> virtual concat.
template <int MODE>
__global__ __launch_bounds__(256) void gemm_bt_kernel(
    const u16* __restrict__ A, const u16* __restrict__ A2, int splitK,
    const u16* __restrict__ Bt, const float* __restrict__ bias,
    int M, int Ntot, int Ktot, int ntiles_n,
    float* __restrict__ outF, u16* __restrict__ outQ, u16* __restrict__ outK,
    u16* __restrict__ outV) {
    __shared__ u16 As[128 * 32];
    __shared__ u16 Bs[128 * 32];
    const int tid = threadIdx.x;
    const int lane = tid & 63, wave = tid >> 6;
    const int wm = wave >> 1, wn = wave & 1;
    const int bm = blockIdx.x / ntiles_n, bn = blockIdx.x % ntiles_n;
    const int brow = bm * 128, bcol = bn * 128;

    f32x4 acc[4][4] = {};

    for (int k0 = 0; k0 < Ktot; k0 += 32) {
        const u16* Ab = (k0 < splitK) ? (A + k0) : (A2 + (k0 - splitK));
#pragma unroll
        for (int it = 0; it < 2; ++it) {
            int chunk = it * 256 + tid;
            int row = chunk >> 2;
            int col = (chunk & 3) * 8;
            int ga = brow + row; if (ga > M - 1) ga = M - 1;
            const u16* gpA = Ab + (size_t)ga * 256 + col;
            const u16* gpB = Bt + (size_t)(bcol + row) * Ktot + k0 + col;
            u16* lpA = As + ((it * 256 + wave * 64) * 8);
            u16* lpB = Bs + ((it * 256 + wave * 64) * 8);
            GLDS16(gpA, lpA);
            GLDS16(gpB, lpB);
        }
        __syncthreads();
        const int kg = lane >> 4, rI = lane & 15;
        bf16x8 a[4], b[4];
#pragma unroll
        for (int m = 0; m < 4; ++m)
            a[m] = *(const bf16x8*)(As + (wm * 64 + m * 16 + rI) * 32 + kg * 8);
#pragma unroll
        for (int n = 0; n < 4; ++n)
            b[n] = *(const bf16x8*)(Bs + (wn * 64 + n * 16 + rI) * 32 + kg * 8);
#pragma unroll
        for (int m = 0; m < 4; ++m)
#pragma unroll
            for (int n = 0; n < 4; ++n)
                acc[m][n] = __builtin_amdgcn_mfma_f32_16x16x32_bf16(a[m], b[n], acc[m][n], 0, 0, 0);
        __syncthreads();
    }

#pragma unroll
    for (int m = 0; m < 4; ++m) {
        int growb = brow + wm * 64 + m * 16 + (lane >> 4) * 4;
#pragma unroll
        for (int n = 0; n < 4; ++n) {
            int gcol = bcol + wn * 64 + n * 16 + (lane & 15);
            float bi = bias[gcol];
#pragma unroll
            for (int r = 0; r < 4; ++r) {
                int grow = growb + r;
                if (grow >= M) continue;
                float c = acc[m][n][r] + bi;
                if (MODE == 0) {
                    outF[(size_t)grow * Ntot + gcol] = c;
                } else {
                    int hh = gcol / 96;
                    int rr = gcol - hh * 96;
                    int sel = rr >> 5;
                    int cc = hh * 32 + (rr & 31);
                    u16* op = sel == 0 ? outQ : (sel == 1 ? outK : outV);
                    op[(size_t)grow * 256 + cc] = f2b(c);
                }
            }
        }
    }
}

extern "C" void kernel_launch(void* const* d_in, const int* in_sizes, int n_in,
                              void* d_out, int out_size, void* d_ws, size_t ws_size,
                              hipStream_t stream) {
    const float* x = (const float*)d_in[0];
    const float* W_qkv = (const float*)d_in[1];
    const float* b_qkv = (const float*)d_in[2];
    const float* W_out = (const float*)d_in[3];
    const float* b_out = (const float*)d_in[4];
    const int* src = (const int*)d_in[5];   // harness passes integer inputs as int32
    const int* dst = (const int*)d_in[6];
    float* out = (float*)d_out;

    char* w = (char*)d_ws;
    size_t off = 0;
    auto alloc = [&](size_t bytes) -> char* {
        char* p = w + off;
        off += (bytes + 255) & ~(size_t)255;
        return p;
    };
    u16* xb = (u16*)alloc((size_t)NN * 256 * 2);
    u16* WbT = (u16*)alloc((size_t)768 * 256 * 2);
    u16* WoT = (u16*)alloc((size_t)256 * 512 * 2);
    u16* Qb = (u16*)alloc((size_t)NN * 256 * 2);
    u16* Kb = (u16*)alloc((size_t)NN * 256 * 2);
    u16* Vb = (u16*)alloc((size_t)NN * 256 * 2);
    u16* msg = Qb;  // alias: attn reads Q[node] fully into regs before writing msg[node]
    int* deg = (int*)alloc((size_t)2 * NN * 4);
    int* cursor = deg + NN;
    int* rowstart = (int*)alloc((size_t)(NN + 1) * 4);
    int* esrc = (int*)alloc((size_t)EE * 4);
    // total workspace ~ 220 MB

    hipMemsetAsync(deg, 0, (size_t)2 * NN * 4, stream);

    cvt_x_kernel<<<25000, 256, 0, stream>>>(x, xb, NN * 256 / 4);
    transpose_bf16_kernel<<<(256 * 768 + 255) / 256, 256, 0, stream>>>(W_qkv, WbT, 256, 768);
    transpose_bf16_kernel<<<(512 * 256 + 255) / 256, 256, 0, stream>>>(W_out, WoT, 512, 256);

    // QKV = xb @ W_qkv + b_qkv  -> de-interleaved Q/K/V (bf16)
    gemm_bt_kernel<1><<<782 * 6, 256, 0, stream>>>(xb, xb, 256, WbT, b_qkv, NN, 768, 256, 6,
                                                   nullptr, Qb, Kb, Vb);

    hist_kernel<<<EE / 256, 256, 0, stream>>>(dst, deg);
    scan_kernel<<<1, 1024, 0, stream>>>(deg, rowstart, NN);
    scatter_kernel<<<EE / 256, 256, 0, stream>>>(src, dst, rowstart, cursor, esrc);

    attn_kernel<<<NN / 4, 256, 0, stream>>>(Qb, Kb, Vb, rowstart, esrc, msg);

    // out = [xb | msg] @ W_out + b_out  (fp32 out)
    gemm_bt_kernel<0><<<782 * 2, 256, 0, stream>>>(xb, msg, 256, WoT, b_out, NN, 256, 512, 2,
                                                   out, nullptr, nullptr, nullptr);
}

// Round 3
// 1094.846 us; speedup vs baseline: 1.0482x; 1.0482x over previous
//
#include <hip/hip_runtime.h>
#include <hip/hip_bf16.h>

typedef unsigned short u16;
typedef short bf16x8 __attribute__((ext_vector_type(8)));
typedef float f32x4 __attribute__((ext_vector_type(4)));

#define NN 100000
#define EE 3200000
static constexpr float COEF = 0.17677669529663687f; // 1/sqrt(32)

__device__ __forceinline__ float b2f(u16 u) { return __uint_as_float(((unsigned)u) << 16); }
__device__ __forceinline__ u16 f2b(float f) {
    unsigned u = __float_as_uint(f);
    unsigned r = (u + 0x7fffu + ((u >> 16) & 1u)) >> 16;
    return (u16)r;
}

#define GLDS16(gp, lp) __builtin_amdgcn_global_load_lds( \
    (const __attribute__((address_space(1))) void*)(gp), \
    (__attribute__((address_space(3))) void*)(lp), 16, 0, 0)

// ---------- conversions ----------
__global__ __launch_bounds__(256) void cvt_x_kernel(const float* __restrict__ in,
                                                    u16* __restrict__ out, int n4) {
    int i = blockIdx.x * 256 + threadIdx.x;
    if (i >= n4) return;
    float4 v = ((const float4*)in)[i];
    ushort4 o;
    o.x = f2b(v.x); o.y = f2b(v.y); o.z = f2b(v.z); o.w = f2b(v.w);
    ((ushort4*)out)[i] = o;
}

__global__ __launch_bounds__(256) void transpose_bf16_kernel(const float* __restrict__ in,
                                                             u16* __restrict__ out, int R, int C) {
    int idx = blockIdx.x * 256 + threadIdx.x;
    if (idx >= R * C) return;
    int r = idx / C, c = idx - r * C;
    out[(size_t)c * R + r] = f2b(in[idx]);
}

// ---------- CSR build ----------
__global__ __launch_bounds__(256) void hist_kernel(const int* __restrict__ dst,
                                                   int* __restrict__ deg) {
    int e = blockIdx.x * 256 + threadIdx.x;
    atomicAdd(&deg[dst[e]], 1);
}

__global__ __launch_bounds__(1024) void scan_kernel(const int* __restrict__ deg,
                                                    int* __restrict__ rowstart, int n) {
    __shared__ int sums[1024];
    int tid = threadIdx.x;
    int per = (n + 1023) >> 10;
    int lo = tid * per;
    int hi = lo + per; if (hi > n) hi = n; if (lo > n) lo = n;
    int s = 0;
    for (int i = lo; i < hi; ++i) s += deg[i];
    sums[tid] = s;
    __syncthreads();
    for (int off = 1; off < 1024; off <<= 1) {
        int v = (tid >= off) ? sums[tid - off] : 0;
        __syncthreads();
        sums[tid] += v;
        __syncthreads();
    }
    int run = (tid == 0) ? 0 : sums[tid - 1];
    for (int i = lo; i < hi; ++i) { rowstart[i] = run; run += deg[i]; }
    if (tid == 1023) rowstart[n] = sums[1023];
}

__global__ __launch_bounds__(256) void scatter_kernel(const int* __restrict__ src,
                                                      const int* __restrict__ dst,
                                                      const int* __restrict__ rowstart,
                                                      int* __restrict__ cursor,
                                                      int* __restrict__ esrc) {
    int e = blockIdx.x * 256 + threadIdx.x;
    int d = dst[e];
    int pos = atomicAdd(&cursor[d], 1);
    esrc[rowstart[d] + pos] = src[e];
}

// ---------- per-node attention: 1 wave per node, 4-edge pipelined online softmax ----
// lane = h*8 + i ; lane owns dims [h*32 + i*4, +4)
// KV layout: [node][512] bf16 — K in cols 0..255, V in cols 256..511.
// Q and msg may alias (Q[node] fully read into regs before msg[node] written).
__global__ __launch_bounds__(256) void attn_kernel(
    const u16* Q, const u16* __restrict__ KV,
    const int* __restrict__ rowstart, const int* __restrict__ esrc,
    u16* msg) {
    int node = blockIdx.x * 4 + (threadIdx.x >> 6);
    int lane = threadIdx.x & 63;
    int r0 = rowstart[node], r1 = rowstart[node + 1];

    float q0, q1, q2, q3;
    {
        ushort4 qa = *(const ushort4*)(Q + (size_t)node * 256 + lane * 4);
        q0 = b2f(qa.x); q1 = b2f(qa.y); q2 = b2f(qa.z); q3 = b2f(qa.w);
    }

    float m = -3.4e38f, denom = 0.0f;
    float a0 = 0, a1 = 0, a2 = 0, a3 = 0;

    int j = r0;
    for (; j + 4 <= r1; j += 4) {
        // 4 uniform index loads, then 8 independent gathers in flight
        int s0 = esrc[j + 0], s1 = esrc[j + 1], s2 = esrc[j + 2], s3 = esrc[j + 3];
        const u16* p0 = KV + (size_t)s0 * 512 + lane * 4;
        const u16* p1 = KV + (size_t)s1 * 512 + lane * 4;
        const u16* p2 = KV + (size_t)s2 * 512 + lane * 4;
        const u16* p3 = KV + (size_t)s3 * 512 + lane * 4;
        ushort4 k0 = *(const ushort4*)p0;
        ushort4 k1 = *(const ushort4*)p1;
        ushort4 k2 = *(const ushort4*)p2;
        ushort4 k3 = *(const ushort4*)p3;
        ushort4 v0 = *(const ushort4*)(p0 + 256);
        ushort4 v1 = *(const ushort4*)(p1 + 256);
        ushort4 v2 = *(const ushort4*)(p2 + 256);
        ushort4 v3 = *(const ushort4*)(p3 + 256);

        // 4 independent dot products; shfl chains interleave
        float d0 = q0 * b2f(k0.x) + q1 * b2f(k0.y) + q2 * b2f(k0.z) + q3 * b2f(k0.w);
        float d1 = q0 * b2f(k1.x) + q1 * b2f(k1.y) + q2 * b2f(k1.z) + q3 * b2f(k1.w);
        float d2 = q0 * b2f(k2.x) + q1 * b2f(k2.y) + q2 * b2f(k2.z) + q3 * b2f(k2.w);
        float d3 = q0 * b2f(k3.x) + q1 * b2f(k3.y) + q2 * b2f(k3.z) + q3 * b2f(k3.w);
        d0 += __shfl_xor(d0, 1); d1 += __shfl_xor(d1, 1);
        d2 += __shfl_xor(d2, 1); d3 += __shfl_xor(d3, 1);
        d0 += __shfl_xor(d0, 2); d1 += __shfl_xor(d1, 2);
        d2 += __shfl_xor(d2, 2); d3 += __shfl_xor(d3, 2);
        d0 += __shfl_xor(d0, 4); d1 += __shfl_xor(d1, 4);
        d2 += __shfl_xor(d2, 4); d3 += __shfl_xor(d3, 4);
        d0 *= COEF; d1 *= COEF; d2 *= COEF; d3 *= COEF;

        // one rescale per 4-edge group (mn uniform across the 8-lane head group)
        float dm = fmaxf(fmaxf(d0, d1), fmaxf(d2, d3));
        float mn = fmaxf(m, dm);
        float scale = __expf(m - mn);
        m = mn;
        float e0 = __expf(d0 - mn), e1 = __expf(d1 - mn);
        float e2 = __expf(d2 - mn), e3 = __expf(d3 - mn);
        denom = denom * scale + ((e0 + e1) + (e2 + e3));
        a0 = a0 * scale + e0 * b2f(v0.x) + e1 * b2f(v1.x) + e2 * b2f(v2.x) + e3 * b2f(v3.x);
        a1 = a1 * scale + e0 * b2f(v0.y) + e1 * b2f(v1.y) + e2 * b2f(v2.y) + e3 * b2f(v3.y);
        a2 = a2 * scale + e0 * b2f(v0.z) + e1 * b2f(v1.z) + e2 * b2f(v2.z) + e3 * b2f(v3.z);
        a3 = a3 * scale + e0 * b2f(v0.w) + e1 * b2f(v1.w) + e2 * b2f(v2.w) + e3 * b2f(v3.w);
    }
    for (; j < r1; ++j) {
        int s = esrc[j];
        const u16* p = KV + (size_t)s * 512 + lane * 4;
        ushort4 ka = *(const ushort4*)p;
        ushort4 va = *(const ushort4*)(p + 256);
        float d = q0 * b2f(ka.x) + q1 * b2f(ka.y) + q2 * b2f(ka.z) + q3 * b2f(ka.w);
        d += __shfl_xor(d, 1);
        d += __shfl_xor(d, 2);
        d += __shfl_xor(d, 4);
        d *= COEF;
        float mn = fmaxf(m, d);
        float scale = __expf(m - mn);
        float ex = __expf(d - mn);
        m = mn;
        denom = denom * scale + ex;
        a0 = a0 * scale + ex * b2f(va.x);
        a1 = a1 * scale + ex * b2f(va.y);
        a2 = a2 * scale + ex * b2f(va.z);
        a3 = a3 * scale + ex * b2f(va.w);
    }
    float inv = 1.0f / fmaxf(denom, 1e-20f);
    ushort4 o;
    o.x = f2b(a0 * inv); o.y = f2b(a1 * inv); o.z = f2b(a2 * inv); o.w = f2b(a3 * inv);
    *(ushort4*)(msg + (size_t)node * 256 + lane * 4) = o;
}

// ---------- bf16 MFMA GEMM: C(M x Ntot) = A(M x Ktot) * Bt(Ntot x Ktot)^T + bias ----------
// MODE 0: fp32 output, plain.  MODE 1: bf16 output de-interleaved into Q / interleaved KV.
// A split: k < splitK reads A, else A2 (both row-stride 256) -> virtual concat.
template <int MODE>
__global__ __launch_bounds__(256) void gemm_bt_kernel(
    const u16* __restrict__ A, const u16* __restrict__ A2, int splitK,
    const u16* __restrict__ Bt, const float* __restrict__ bias,
    int M, int Ntot, int Ktot, int ntiles_n,
    float* __restrict__ outF, u16* __restrict__ outQ, u16* __restrict__ outKV) {
    __shared__ u16 As[128 * 32];
    __shared__ u16 Bs[128 * 32];
    const int tid = threadIdx.x;
    const int lane = tid & 63, wave = tid >> 6;
    const int wm = wave >> 1, wn = wave & 1;
    const int bm = blockIdx.x / ntiles_n, bn = blockIdx.x % ntiles_n;
    const int brow = bm * 128, bcol = bn * 128;

    f32x4 acc[4][4] = {};

    for (int k0 = 0; k0 < Ktot; k0 += 32) {
        const u16* Ab = (k0 < splitK) ? (A + k0) : (A2 + (k0 - splitK));
#pragma unroll
        for (int it = 0; it < 2; ++it) {
            int chunk = it * 256 + tid;
            int row = chunk >> 2;
            int col = (chunk & 3) * 8;
            int ga = brow + row; if (ga > M - 1) ga = M - 1;
            const u16* gpA = Ab + (size_t)ga * 256 + col;
            const u16* gpB = Bt + (size_t)(bcol + row) * Ktot + k0 + col;
            u16* lpA = As + ((it * 256 + wave * 64) * 8);
            u16* lpB = Bs + ((it * 256 + wave * 64) * 8);
            GLDS16(gpA, lpA);
            GLDS16(gpB, lpB);
        }
        __syncthreads();
        const int kg = lane >> 4, rI = lane & 15;
        bf16x8 a[4], b[4];
#pragma unroll
        for (int m = 0; m < 4; ++m)
            a[m] = *(const bf16x8*)(As + (wm * 64 + m * 16 + rI) * 32 + kg * 8);
#pragma unroll
        for (int n = 0; n < 4; ++n)
            b[n] = *(const bf16x8*)(Bs + (wn * 64 + n * 16 + rI) * 32 + kg * 8);
#pragma unroll
        for (int m = 0; m < 4; ++m)
#pragma unroll
            for (int n = 0; n < 4; ++n)
                acc[m][n] = __builtin_amdgcn_mfma_f32_16x16x32_bf16(a[m], b[n], acc[m][n], 0, 0, 0);
        __syncthreads();
    }

#pragma unroll
    for (int m = 0; m < 4; ++m) {
        int growb = brow + wm * 64 + m * 16 + (lane >> 4) * 4;
#pragma unroll
        for (int n = 0; n < 4; ++n) {
            int gcol = bcol + wn * 64 + n * 16 + (lane & 15);
            float bi = bias[gcol];
#pragma unroll
            for (int r = 0; r < 4; ++r) {
                int grow = growb + r;
                if (grow >= M) continue;
                float c = acc[m][n][r] + bi;
                if (MODE == 0) {
                    outF[(size_t)grow * Ntot + gcol] = c;
                } else {
                    int hh = gcol / 96;
                    int rr = gcol - hh * 96;
                    int sel = rr >> 5;
                    int cc = hh * 32 + (rr & 31);
                    if (sel == 0)
                        outQ[(size_t)grow * 256 + cc] = f2b(c);
                    else
                        outKV[(size_t)grow * 512 + (sel - 1) * 256 + cc] = f2b(c);
                }
            }
        }
    }
}

extern "C" void kernel_launch(void* const* d_in, const int* in_sizes, int n_in,
                              void* d_out, int out_size, void* d_ws, size_t ws_size,
                              hipStream_t stream) {
    const float* x = (const float*)d_in[0];
    const float* W_qkv = (const float*)d_in[1];
    const float* b_qkv = (const float*)d_in[2];
    const float* W_out = (const float*)d_in[3];
    const float* b_out = (const float*)d_in[4];
    const int* src = (const int*)d_in[5];
    const int* dst = (const int*)d_in[6];
    float* out = (float*)d_out;

    char* w = (char*)d_ws;
    size_t off = 0;
    auto alloc = [&](size_t bytes) -> char* {
        char* p = w + off;
        off += (bytes + 255) & ~(size_t)255;
        return p;
    };
    u16* xb = (u16*)alloc((size_t)NN * 256 * 2);
    u16* WbT = (u16*)alloc((size_t)768 * 256 * 2);
    u16* WoT = (u16*)alloc((size_t)256 * 512 * 2);
    u16* Qb = (u16*)alloc((size_t)NN * 256 * 2);
    u16* KVb = (u16*)alloc((size_t)NN * 512 * 2);
    u16* msg = Qb;  // alias: attn reads Q[node] fully into regs before writing msg[node]
    int* deg = (int*)alloc((size_t)2 * NN * 4);
    int* cursor = deg + NN;
    int* rowstart = (int*)alloc((size_t)(NN + 1) * 4);
    int* esrc = (int*)alloc((size_t)EE * 4);
    // total workspace ~ 220 MB

    hipMemsetAsync(deg, 0, (size_t)2 * NN * 4, stream);

    cvt_x_kernel<<<25000, 256, 0, stream>>>(x, xb, NN * 256 / 4);
    transpose_bf16_kernel<<<(256 * 768 + 255) / 256, 256, 0, stream>>>(W_qkv, WbT, 256, 768);
    transpose_bf16_kernel<<<(512 * 256 + 255) / 256, 256, 0, stream>>>(W_out, WoT, 512, 256);

    // QKV = xb @ W_qkv + b_qkv  -> Q (de-interleaved) + KV (K|V interleaved per node)
    gemm_bt_kernel<1><<<782 * 6, 256, 0, stream>>>(xb, xb, 256, WbT, b_qkv, NN, 768, 256, 6,
                                                   nullptr, Qb, KVb);

    hist_kernel<<<EE / 256, 256, 0, stream>>>(dst, deg);
    scan_kernel<<<1, 1024, 0, stream>>>(deg, rowstart, NN);
    scatter_kernel<<<EE / 256, 256, 0, stream>>>(src, dst, rowstart, cursor, esrc);

    attn_kernel<<<NN / 4, 256, 0, stream>>>(Qb, KVb, rowstart, esrc, msg);

    // out = [xb | msg] @ W_out + b_out  (fp32 out)
    gemm_bt_kernel<0><<<782 * 2, 256, 0, stream>>>(xb, msg, 256, WoT, b_out, NN, 256, 512, 2,
                                                   out, nullptr, nullptr);
}

// Round 4
// 1092.924 us; speedup vs baseline: 1.0500x; 1.0018x over previous
//
#include <hip/hip_runtime.h>
#include <hip/hip_bf16.h>

typedef unsigned short u16;
typedef short bf16x8 __attribute__((ext_vector_type(8)));
typedef float f32x4 __attribute__((ext_vector_type(4)));

#define NN 100000
#define EE 3200000
static constexpr float COEF = 0.17677669529663687f; // 1/sqrt(32)

__device__ __forceinline__ float b2f(u16 u) { return __uint_as_float(((unsigned)u) << 16); }
__device__ __forceinline__ u16 f2b(float f) {
    unsigned u = __float_as_uint(f);
    unsigned r = (u + 0x7fffu + ((u >> 16) & 1u)) >> 16;
    return (u16)r;
}

#define B2LO(w) __uint_as_float((w) << 16)
#define B2HI(w) __uint_as_float((w) & 0xffff0000u)

#define GLDS16(gp, lp) __builtin_amdgcn_global_load_lds( \
    (const __attribute__((address_space(1))) void*)(gp), \
    (__attribute__((address_space(3))) void*)(lp), 16, 0, 0)

// ---------- conversions ----------
__global__ __launch_bounds__(256) void cvt_x_kernel(const float* __restrict__ in,
                                                    u16* __restrict__ out, int n4) {
    int i = blockIdx.x * 256 + threadIdx.x;
    if (i >= n4) return;
    float4 v = ((const float4*)in)[i];
    ushort4 o;
    o.x = f2b(v.x); o.y = f2b(v.y); o.z = f2b(v.z); o.w = f2b(v.w);
    ((ushort4*)out)[i] = o;
}

__global__ __launch_bounds__(256) void transpose_bf16_kernel(const float* __restrict__ in,
                                                             u16* __restrict__ out, int R, int C) {
    int idx = blockIdx.x * 256 + threadIdx.x;
    if (idx >= R * C) return;
    int r = idx / C, c = idx - r * C;
    out[(size_t)c * R + r] = f2b(in[idx]);
}

// ---------- CSR build ----------
__global__ __launch_bounds__(256) void hist_kernel(const int* __restrict__ dst,
                                                   int* __restrict__ deg) {
    int e = blockIdx.x * 256 + threadIdx.x;
    atomicAdd(&deg[dst[e]], 1);
}

__global__ __launch_bounds__(1024) void scan_kernel(const int* __restrict__ deg,
                                                    int* __restrict__ rowstart, int n) {
    __shared__ int sums[1024];
    int tid = threadIdx.x;
    int per = (n + 1023) >> 10;
    int lo = tid * per;
    int hi = lo + per; if (hi > n) hi = n; if (lo > n) lo = n;
    int s = 0;
    for (int i = lo; i < hi; ++i) s += deg[i];
    sums[tid] = s;
    __syncthreads();
    for (int off = 1; off < 1024; off <<= 1) {
        int v = (tid >= off) ? sums[tid - off] : 0;
        __syncthreads();
        sums[tid] += v;
        __syncthreads();
    }
    int run = (tid == 0) ? 0 : sums[tid - 1];
    for (int i = lo; i < hi; ++i) { rowstart[i] = run; run += deg[i]; }
    if (tid == 1023) rowstart[n] = sums[1023];
}

__global__ __launch_bounds__(256) void scatter_kernel(const int* __restrict__ src,
                                                      const int* __restrict__ dst,
                                                      const int* __restrict__ rowstart,
                                                      int* __restrict__ cursor,
                                                      int* __restrict__ esrc) {
    int e = blockIdx.x * 256 + threadIdx.x;
    int d = dst[e];
    int pos = atomicAdd(&cursor[d], 1);
    esrc[rowstart[d] + pos] = src[e];
}

// ---------- per-node attention: 1 wave per node; lane = (head, edge_slot) ----------
// h = lane>>3 (8 heads), slot = lane&7 (8 edge slots per iteration).
// Each lane computes the FULL 32-dim dot for its (edge, head): no per-edge cross-lane.
// Private online softmax per lane (defer-max, threshold 4); one butterfly merge per node.
// KV layout: [node][512] bf16 — K in cols 0..255, V in cols 256..511.
// Q and msg may alias (Q[node] fully read into regs before msg[node] written).
__global__ __launch_bounds__(256) void attn_kernel(
    const u16* Q, const u16* __restrict__ KV,
    const int* __restrict__ rowstart, const int* __restrict__ esrc,
    u16* msg) {
    int node = blockIdx.x * 4 + (threadIdx.x >> 6);
    int lane = threadIdx.x & 63;
    int h = lane >> 3;
    int slot = lane & 7;
    int r0 = rowstart[node], r1 = rowstart[node + 1];

    // q for head h, pre-scaled by COEF (32 floats, all indices compile-time)
    float q[32];
    {
        const uint4* qp = (const uint4*)(Q + (size_t)node * 256 + h * 32);
#pragma unroll
        for (int i = 0; i < 4; ++i) {
            uint4 wv = qp[i];
            q[i * 8 + 0] = B2LO(wv.x) * COEF; q[i * 8 + 1] = B2HI(wv.x) * COEF;
            q[i * 8 + 2] = B2LO(wv.y) * COEF; q[i * 8 + 3] = B2HI(wv.y) * COEF;
            q[i * 8 + 4] = B2LO(wv.z) * COEF; q[i * 8 + 5] = B2HI(wv.z) * COEF;
            q[i * 8 + 6] = B2LO(wv.w) * COEF; q[i * 8 + 7] = B2HI(wv.w) * COEF;
        }
    }

    float m = -3.0e38f, denom = 0.0f;
    float acc[32];
#pragma unroll
    for (int i = 0; i < 32; ++i) acc[i] = 0.0f;

#define DOT2(w, i0) d += q[i0] * B2LO(w) + q[(i0) + 1] * B2HI(w)
#define ACC2(w, i0) { acc[i0] = __builtin_fmaf(ex, B2LO(w), acc[i0]); \
                      acc[(i0) + 1] = __builtin_fmaf(ex, B2HI(w), acc[(i0) + 1]); }

    for (int base = r0; base < r1; base += 8) {
        int myj = base + slot;
        bool valid = myj < r1;
        int jj = valid ? myj : r1 - 1;
        int s = esrc[jj];
        const uint4* kp = (const uint4*)(KV + (size_t)s * 512 + h * 32);
        // 8 x dwordx4 in flight: full K and V 32-dim chunks for this (edge, head)
        uint4 k0 = kp[0], k1 = kp[1], k2 = kp[2], k3 = kp[3];
        uint4 v0 = kp[32], v1 = kp[33], v2 = kp[34], v3 = kp[35]; // +512B = V

        float d = 0.0f;
        DOT2(k0.x, 0);  DOT2(k0.y, 2);  DOT2(k0.z, 4);  DOT2(k0.w, 6);
        DOT2(k1.x, 8);  DOT2(k1.y, 10); DOT2(k1.z, 12); DOT2(k1.w, 14);
        DOT2(k2.x, 16); DOT2(k2.y, 18); DOT2(k2.z, 20); DOT2(k2.w, 22);
        DOT2(k3.x, 24); DOT2(k3.y, 26); DOT2(k3.z, 28); DOT2(k3.w, 30);
        if (!valid) d = -3.0e38f;

        // defer-max online softmax: rescale only when max grows by > 4
        if (d > m + 4.0f) {
            float scale = __expf(m - d);
            m = d;
            denom *= scale;
#pragma unroll
            for (int i = 0; i < 32; ++i) acc[i] *= scale;
        }
        float ex = valid ? __expf(d - m) : 0.0f;   // bounded by e^4
        denom += ex;
        ACC2(v0.x, 0);  ACC2(v0.y, 2);  ACC2(v0.z, 4);  ACC2(v0.w, 6);
        ACC2(v1.x, 8);  ACC2(v1.y, 10); ACC2(v1.z, 12); ACC2(v1.w, 14);
        ACC2(v2.x, 16); ACC2(v2.y, 18); ACC2(v2.z, 20); ACC2(v2.w, 22);
        ACC2(v3.x, 24); ACC2(v3.y, 26); ACC2(v3.z, 28); ACC2(v3.w, 30);
    }

    // ---- per-node merge across the 8 slots (same-h lanes are consecutive) ----
    float mg = fmaxf(m, __shfl_xor(m, 1));
    mg = fmaxf(mg, __shfl_xor(mg, 2));
    mg = fmaxf(mg, __shfl_xor(mg, 4));
    float f = __expf(m - mg);       // m=-3e38 & mg finite -> 0 ; all -3e38 -> 1 (denom 0)
    float dn = denom * f;
    dn += __shfl_xor(dn, 1);
    dn += __shfl_xor(dn, 2);
    dn += __shfl_xor(dn, 4);
#pragma unroll
    for (int i = 0; i < 32; ++i) acc[i] *= f;

    // halving butterfly: each round keeps half the dims, exchanges the other half
    float t16[16];
#pragma unroll
    for (int i = 0; i < 16; ++i) {
        float send = (slot & 1) ? acc[i] : acc[i + 16];
        float recv = __shfl_xor(send, 1);
        t16[i] = ((slot & 1) ? acc[i + 16] : acc[i]) + recv;
    }
    float t8[8];
#pragma unroll
    for (int i = 0; i < 8; ++i) {
        float send = (slot & 2) ? t16[i] : t16[i + 8];
        float recv = __shfl_xor(send, 2);
        t8[i] = ((slot & 2) ? t16[i + 8] : t16[i]) + recv;
    }
    float t4[4];
#pragma unroll
    for (int i = 0; i < 4; ++i) {
        float send = (slot & 4) ? t8[i] : t8[i + 4];
        float recv = __shfl_xor(send, 4);
        t4[i] = ((slot & 4) ? t8[i + 4] : t8[i]) + recv;
    }
    int dimbase = ((slot & 1) << 4) | ((slot & 2) << 2) | (slot & 4);

    float inv = 1.0f / fmaxf(dn, 1e-20f);
    ushort4 o;
    o.x = f2b(t4[0] * inv); o.y = f2b(t4[1] * inv);
    o.z = f2b(t4[2] * inv); o.w = f2b(t4[3] * inv);
    *(ushort4*)(msg + (size_t)node * 256 + h * 32 + dimbase) = o;
}

// ---------- bf16 MFMA GEMM: C(M x Ntot) = A(M x Ktot) * Bt(Ntot x Ktot)^T + bias ----------
// MODE 0: fp32 output, plain.  MODE 1: bf16 output de-interleaved into Q / interleaved KV.
// A split: k < splitK reads A, else A2 (both row-stride 256) -> virtual concat.
template <int MODE>
__global__ __launch_bounds__(256) void gemm_bt_kernel(
    const u16* __restrict__ A, const u16* __restrict__ A2, int splitK,
    const u16* __restrict__ Bt, const float* __restrict__ bias,
    int M, int Ntot, int Ktot, int ntiles_n,
    float* __restrict__ outF, u16* __restrict__ outQ, u16* __restrict__ outKV) {
    __shared__ u16 As[128 * 32];
    __shared__ u16 Bs[128 * 32];
    const int tid = threadIdx.x;
    const int lane = tid & 63, wave = tid >> 6;
    const int wm = wave >> 1, wn = wave & 1;
    const int bm = blockIdx.x / ntiles_n, bn = blockIdx.x % ntiles_n;
    const int brow = bm * 128, bcol = bn * 128;

    f32x4 acc[4][4] = {};

    for (int k0 = 0; k0 < Ktot; k0 += 32) {
        const u16* Ab = (k0 < splitK) ? (A + k0) : (A2 + (k0 - splitK));
#pragma unroll
        for (int it = 0; it < 2; ++it) {
            int chunk = it * 256 + tid;
            int row = chunk >> 2;
            int col = (chunk & 3) * 8;
            int ga = brow + row; if (ga > M - 1) ga = M - 1;
            const u16* gpA = Ab + (size_t)ga * 256 + col;
            const u16* gpB = Bt + (size_t)(bcol + row) * Ktot + k0 + col;
            u16* lpA = As + ((it * 256 + wave * 64) * 8);
            u16* lpB = Bs + ((it * 256 + wave * 64) * 8);
            GLDS16(gpA, lpA);
            GLDS16(gpB, lpB);
        }
        __syncthreads();
        const int kg = lane >> 4, rI = lane & 15;
        bf16x8 a[4], b[4];
#pragma unroll
        for (int m = 0; m < 4; ++m)
            a[m] = *(const bf16x8*)(As + (wm * 64 + m * 16 + rI) * 32 + kg * 8);
#pragma unroll
        for (int n = 0; n < 4; ++n)
            b[n] = *(const bf16x8*)(Bs + (wn * 64 + n * 16 + rI) * 32 + kg * 8);
#pragma unroll
        for (int m = 0; m < 4; ++m)
#pragma unroll
            for (int n = 0; n < 4; ++n)
                acc[m][n] = __builtin_amdgcn_mfma_f32_16x16x32_bf16(a[m], b[n], acc[m][n], 0, 0, 0);
        __syncthreads();
    }

#pragma unroll
    for (int m = 0; m < 4; ++m) {
        int growb = brow + wm * 64 + m * 16 + (lane >> 4) * 4;
#pragma unroll
        for (int n = 0; n < 4; ++n) {
            int gcol = bcol + wn * 64 + n * 16 + (lane & 15);
            float bi = bias[gcol];
#pragma unroll
            for (int r = 0; r < 4; ++r) {
                int grow = growb + r;
                if (grow >= M) continue;
                float c = acc[m][n][r] + bi;
                if (MODE == 0) {
                    outF[(size_t)grow * Ntot + gcol] = c;
                } else {
                    int hh = gcol / 96;
                    int rr = gcol - hh * 96;
                    int sel = rr >> 5;
                    int cc = hh * 32 + (rr & 31);
                    if (sel == 0)
                        outQ[(size_t)grow * 256 + cc] = f2b(c);
                    else
                        outKV[(size_t)grow * 512 + (sel - 1) * 256 + cc] = f2b(c);
                }
            }
        }
    }
}

extern "C" void kernel_launch(void* const* d_in, const int* in_sizes, int n_in,
                              void* d_out, int out_size, void* d_ws, size_t ws_size,
                              hipStream_t stream) {
    const float* x = (const float*)d_in[0];
    const float* W_qkv = (const float*)d_in[1];
    const float* b_qkv = (const float*)d_in[2];
    const float* W_out = (const float*)d_in[3];
    const float* b_out = (const float*)d_in[4];
    const int* src = (const int*)d_in[5];
    const int* dst = (const int*)d_in[6];
    float* out = (float*)d_out;

    char* w = (char*)d_ws;
    size_t off = 0;
    auto alloc = [&](size_t bytes) -> char* {
        char* p = w + off;
        off += (bytes + 255) & ~(size_t)255;
        return p;
    };
    u16* xb = (u16*)alloc((size_t)NN * 256 * 2);
    u16* WbT = (u16*)alloc((size_t)768 * 256 * 2);
    u16* WoT = (u16*)alloc((size_t)256 * 512 * 2);
    u16* Qb = (u16*)alloc((size_t)NN * 256 * 2);
    u16* KVb = (u16*)alloc((size_t)NN * 512 * 2);
    u16* msg = Qb;  // alias: attn reads Q[node] fully into regs before writing msg[node]
    int* deg = (int*)alloc((size_t)2 * NN * 4);
    int* cursor = deg + NN;
    int* rowstart = (int*)alloc((size_t)(NN + 1) * 4);
    int* esrc = (int*)alloc((size_t)EE * 4);
    // total workspace ~ 220 MB

    hipMemsetAsync(deg, 0, (size_t)2 * NN * 4, stream);

    cvt_x_kernel<<<25000, 256, 0, stream>>>(x, xb, NN * 256 / 4);
    transpose_bf16_kernel<<<(256 * 768 + 255) / 256, 256, 0, stream>>>(W_qkv, WbT, 256, 768);
    transpose_bf16_kernel<<<(512 * 256 + 255) / 256, 256, 0, stream>>>(W_out, WoT, 512, 256);

    // QKV = xb @ W_qkv + b_qkv  -> Q (de-interleaved) + KV (K|V interleaved per node)
    gemm_bt_kernel<1><<<782 * 6, 256, 0, stream>>>(xb, xb, 256, WbT, b_qkv, NN, 768, 256, 6,
                                                   nullptr, Qb, KVb);

    hist_kernel<<<EE / 256, 256, 0, stream>>>(dst, deg);
    scan_kernel<<<1, 1024, 0, stream>>>(deg, rowstart, NN);
    scatter_kernel<<<EE / 256, 256, 0, stream>>>(src, dst, rowstart, cursor, esrc);

    attn_kernel<<<NN / 4, 256, 0, stream>>>(Qb, KVb, rowstart, esrc, msg);

    // out = [xb | msg] @ W_out + b_out  (fp32 out)
    gemm_bt_kernel<0><<<782 * 2, 256, 0, stream>>>(xb, msg, 256, WoT, b_out, NN, 256, 512, 2,
                                                   out, nullptr, nullptr);
}

// Round 5
// 750.073 us; speedup vs baseline: 1.5300x; 1.4571x over previous
//
#include <hip/hip_runtime.h>
#include <hip/hip_bf16.h>

typedef unsigned short u16;
typedef unsigned char u8;
typedef short bf16x8 __attribute__((ext_vector_type(8)));
typedef float f32x4 __attribute__((ext_vector_type(4)));
typedef float f32x2 __attribute__((ext_vector_type(2)));

#define NN 100000
#define EE 3200000
#define BUCKET 128
static constexpr float COEF = 0.17677669529663687f; // 1/sqrt(32)

__device__ __forceinline__ u16 f2b(float f) {
    unsigned u = __float_as_uint(f);
    unsigned r = (u + 0x7fffu + ((u >> 16) & 1u)) >> 16;
    return (u16)r;
}

#define B2LO(w) __uint_as_float((w) << 16)
#define B2HI(w) __uint_as_float((w) & 0xffff0000u)

#define GLDS16(gp, lp) __builtin_amdgcn_global_load_lds( \
    (const __attribute__((address_space(1))) void*)(gp), \
    (__attribute__((address_space(3))) void*)(lp), 16, 0, 0)

// ---------- conversions ----------
__global__ __launch_bounds__(256) void cvt_x_kernel(const float* __restrict__ in,
                                                    u16* __restrict__ out, int n4) {
    int i = blockIdx.x * 256 + threadIdx.x;
    if (i >= n4) return;
    float4 v = ((const float4*)in)[i];
    ushort4 o;
    o.x = f2b(v.x); o.y = f2b(v.y); o.z = f2b(v.z); o.w = f2b(v.w);
    ((ushort4*)out)[i] = o;
}

__global__ __launch_bounds__(256) void transpose_bf16_kernel(const float* __restrict__ in,
                                                             u16* __restrict__ out, int R, int C) {
    int idx = blockIdx.x * 256 + threadIdx.x;
    if (idx >= R * C) return;
    int r = idx / C, c = idx - r * C;
    out[(size_t)c * R + r] = f2b(in[idx]);
}

// ---------- edge bucketing (replaces hist+scan+scatter) ----------
__global__ __launch_bounds__(256) void edge_bucket_kernel(const int* __restrict__ src,
                                                          const int* __restrict__ dst,
                                                          int* __restrict__ cnt,
                                                          int* __restrict__ esrc) {
    int e = blockIdx.x * 256 + threadIdx.x;
    int d = dst[e];
    int pos = atomicAdd(&cnt[d], 1);
    esrc[(size_t)d * BUCKET + pos] = src[e];
}

// ---------- per-node attention: 1 wave per node; lane = (head, edge_slot) ----------
// h = lane>>3 (8 heads), slot = lane&7 (8 edge slots per iteration).
// Each lane computes the FULL 32-dim dot for its (edge, head).
// K: [node][256] bf16 (512B/row). V: [node][256] fp8 e4m3 (256B/row).
// Private online softmax per lane (defer-max thr=4); one butterfly merge per node.
// Q and msg may alias (Q[node] fully read into regs before msg[node] written).
__global__ __launch_bounds__(256) void attn_kernel(
    const u16* Q, const u16* __restrict__ K, const u8* __restrict__ V,
    const int* __restrict__ cnt, const int* __restrict__ esrc,
    u16* msg) {
    int node = blockIdx.x * 4 + (threadIdx.x >> 6);
    int lane = threadIdx.x & 63;
    int h = lane >> 3;
    int slot = lane & 7;
    int r0 = node * BUCKET;
    int r1 = r0 + cnt[node];

    float q[32];
    {
        const uint4* qp = (const uint4*)(Q + (size_t)node * 256 + h * 32);
#pragma unroll
        for (int i = 0; i < 4; ++i) {
            uint4 wv = qp[i];
            q[i * 8 + 0] = B2LO(wv.x) * COEF; q[i * 8 + 1] = B2HI(wv.x) * COEF;
            q[i * 8 + 2] = B2LO(wv.y) * COEF; q[i * 8 + 3] = B2HI(wv.y) * COEF;
            q[i * 8 + 4] = B2LO(wv.z) * COEF; q[i * 8 + 5] = B2HI(wv.z) * COEF;
            q[i * 8 + 6] = B2LO(wv.w) * COEF; q[i * 8 + 7] = B2HI(wv.w) * COEF;
        }
    }

    float m = -3.0e38f, denom = 0.0f;
    float acc[32];
#pragma unroll
    for (int i = 0; i < 32; ++i) acc[i] = 0.0f;

#define DOT2(w, i0) d += q[i0] * B2LO(w) + q[(i0) + 1] * B2HI(w)
#define ACC4(u, i0) { f32x2 lo = __builtin_amdgcn_cvt_pk_f32_fp8(u, false); \
                      f32x2 hi = __builtin_amdgcn_cvt_pk_f32_fp8(u, true);  \
                      acc[i0]     = __builtin_fmaf(ex, lo[0], acc[i0]);     \
                      acc[(i0)+1] = __builtin_fmaf(ex, lo[1], acc[(i0)+1]); \
                      acc[(i0)+2] = __builtin_fmaf(ex, hi[0], acc[(i0)+2]); \
                      acc[(i0)+3] = __builtin_fmaf(ex, hi[1], acc[(i0)+3]); }

    for (int base = r0; base < r1; base += 8) {
        int myj = base + slot;
        bool valid = myj < r1;
        int s = valid ? esrc[myj] : 0;      // exec-masked load; s=0 rows are cached+unused
        const uint4* kp = (const uint4*)(K + (size_t)s * 256 + h * 32);
        const uint4* vp = (const uint4*)(V + (size_t)s * 256 + h * 32);
        uint4 k0 = kp[0], k1 = kp[1], k2 = kp[2], k3 = kp[3];
        uint4 va = vp[0], vb = vp[1];       // 32 fp8 values

        float d = 0.0f;
        DOT2(k0.x, 0);  DOT2(k0.y, 2);  DOT2(k0.z, 4);  DOT2(k0.w, 6);
        DOT2(k1.x, 8);  DOT2(k1.y, 10); DOT2(k1.z, 12); DOT2(k1.w, 14);
        DOT2(k2.x, 16); DOT2(k2.y, 18); DOT2(k2.z, 20); DOT2(k2.w, 22);
        DOT2(k3.x, 24); DOT2(k3.y, 26); DOT2(k3.z, 28); DOT2(k3.w, 30);
        if (!valid) d = -3.0e38f;

        if (d > m + 4.0f) {                 // defer-max: rescale only on big growth
            float scale = __expf(m - d);
            m = d;
            denom *= scale;
#pragma unroll
            for (int i = 0; i < 32; ++i) acc[i] *= scale;
        }
        float ex = valid ? __expf(d - m) : 0.0f;   // bounded by e^4
        denom += ex;
        ACC4(va.x, 0);  ACC4(va.y, 4);  ACC4(va.z, 8);  ACC4(va.w, 12);
        ACC4(vb.x, 16); ACC4(vb.y, 20); ACC4(vb.z, 24); ACC4(vb.w, 28);
    }

    // ---- per-node merge across the 8 slots ----
    float mg = fmaxf(m, __shfl_xor(m, 1));
    mg = fmaxf(mg, __shfl_xor(mg, 2));
    mg = fmaxf(mg, __shfl_xor(mg, 4));
    float f = __expf(m - mg);
    float dn = denom * f;
    dn += __shfl_xor(dn, 1);
    dn += __shfl_xor(dn, 2);
    dn += __shfl_xor(dn, 4);
#pragma unroll
    for (int i = 0; i < 32; ++i) acc[i] *= f;

    float t16[16];
#pragma unroll
    for (int i = 0; i < 16; ++i) {
        float send = (slot & 1) ? acc[i] : acc[i + 16];
        float recv = __shfl_xor(send, 1);
        t16[i] = ((slot & 1) ? acc[i + 16] : acc[i]) + recv;
    }
    float t8[8];
#pragma unroll
    for (int i = 0; i < 8; ++i) {
        float send = (slot & 2) ? t16[i] : t16[i + 8];
        float recv = __shfl_xor(send, 2);
        t8[i] = ((slot & 2) ? t16[i + 8] : t16[i]) + recv;
    }
    float t4[4];
#pragma unroll
    for (int i = 0; i < 4; ++i) {
        float send = (slot & 4) ? t8[i] : t8[i + 4];
        float recv = __shfl_xor(send, 4);
        t4[i] = ((slot & 4) ? t8[i + 4] : t8[i]) + recv;
    }
    int dimbase = ((slot & 1) << 4) | ((slot & 2) << 2) | (slot & 4);

    float inv = 1.0f / fmaxf(dn, 1e-20f);
    ushort4 o;
    o.x = f2b(t4[0] * inv); o.y = f2b(t4[1] * inv);
    o.z = f2b(t4[2] * inv); o.w = f2b(t4[3] * inv);
    *(ushort4*)(msg + (size_t)node * 256 + h * 32 + dimbase) = o;
}

// ---------- bf16 MFMA GEMM, BK=64, XOR-swizzled LDS ----------
// C(M x Ntot) = A(M x Ktot) * Bt(Ntot x Ktot)^T + bias
// MODE 0: fp32 out. MODE 1: Q,K bf16 + V fp8, de-interleaved.
// A row stride fixed 256; k<splitK reads A else A2 (virtual concat).
template <int MODE>
__global__ __launch_bounds__(256) void gemm_bt_kernel(
    const u16* __restrict__ A, const u16* __restrict__ A2, int splitK,
    const u16* __restrict__ Bt, const float* __restrict__ bias,
    int M, int Ntot, int Ktot, int ntiles_n,
    float* __restrict__ outF, u16* __restrict__ outQ, u16* __restrict__ outK,
    u8* __restrict__ outV) {
    __shared__ u16 As[128 * 64];
    __shared__ u16 Bs[128 * 64];
    const int tid = threadIdx.x;
    const int lane = tid & 63, wave = tid >> 6;
    const int wm = wave >> 1, wn = wave & 1;
    const int bm = blockIdx.x / ntiles_n, bn = blockIdx.x % ntiles_n;
    const int brow = bm * 128, bcol = bn * 128;

    f32x4 acc[4][4] = {};

    for (int k0 = 0; k0 < Ktot; k0 += 64) {
        const u16* Ab = (k0 < splitK) ? (A + k0) : (A2 + (k0 - splitK));
#pragma unroll
        for (int it = 0; it < 4; ++it) {
            int chunk = it * 256 + tid;          // 0..1023
            int row = chunk >> 3;                // 0..127
            int cg = chunk & 7;                  // 16B column-group
            int gcg = cg ^ (row & 7);            // inverse-swizzled global source
            int ga = brow + row; if (ga > M - 1) ga = M - 1;
            GLDS16(Ab + (size_t)ga * 256 + gcg * 8, As + (it * 256 + wave * 64) * 8);
            GLDS16(Bt + (size_t)(bcol + row) * Ktot + k0 + gcg * 8,
                   Bs + (it * 256 + wave * 64) * 8);
        }
        __syncthreads();
        const int kg = lane >> 4, rI = lane & 15, rx = lane & 7;
#pragma unroll
        for (int ks = 0; ks < 2; ++ks) {
            bf16x8 a[4], b[4];
#pragma unroll
            for (int m = 0; m < 4; ++m)
                a[m] = *(const bf16x8*)(As + (wm * 64 + m * 16 + rI) * 64 +
                                        (((ks * 4 + kg) ^ rx) * 8));
#pragma unroll
            for (int n = 0; n < 4; ++n)
                b[n] = *(const bf16x8*)(Bs + (wn * 64 + n * 16 + rI) * 64 +
                                        (((ks * 4 + kg) ^ rx) * 8));
#pragma unroll
            for (int m = 0; m < 4; ++m)
#pragma unroll
                for (int n = 0; n < 4; ++n)
                    acc[m][n] = __builtin_amdgcn_mfma_f32_16x16x32_bf16(a[m], b[n], acc[m][n], 0, 0, 0);
        }
        __syncthreads();
    }

#pragma unroll
    for (int m = 0; m < 4; ++m) {
        int growb = brow + wm * 64 + m * 16 + (lane >> 4) * 4;
#pragma unroll
        for (int n = 0; n < 4; ++n) {
            int gcol = bcol + wn * 64 + n * 16 + (lane & 15);
            float bi = bias[gcol];
#pragma unroll
            for (int r = 0; r < 4; ++r) {
                int grow = growb + r;
                if (grow >= M) continue;
                float c = acc[m][n][r] + bi;
                if (MODE == 0) {
                    outF[(size_t)grow * Ntot + gcol] = c;
                } else {
                    int hh = gcol / 96;
                    int rr = gcol - hh * 96;
                    int sel = rr >> 5;
                    int cc = hh * 32 + (rr & 31);
                    if (sel == 0)
                        outQ[(size_t)grow * 256 + cc] = f2b(c);
                    else if (sel == 1)
                        outK[(size_t)grow * 256 + cc] = f2b(c);
                    else {
                        unsigned pv = __builtin_amdgcn_cvt_pk_fp8_f32(c, c, 0, false);
                        outV[(size_t)grow * 256 + cc] = (u8)(pv & 0xff);
                    }
                }
            }
        }
    }
}

extern "C" void kernel_launch(void* const* d_in, const int* in_sizes, int n_in,
                              void* d_out, int out_size, void* d_ws, size_t ws_size,
                              hipStream_t stream) {
    const float* x = (const float*)d_in[0];
    const float* W_qkv = (const float*)d_in[1];
    const float* b_qkv = (const float*)d_in[2];
    const float* W_out = (const float*)d_in[3];
    const float* b_out = (const float*)d_in[4];
    const int* src = (const int*)d_in[5];
    const int* dst = (const int*)d_in[6];
    float* out = (float*)d_out;

    char* w = (char*)d_ws;
    size_t off = 0;
    auto alloc = [&](size_t bytes) -> char* {
        char* p = w + off;
        off += (bytes + 255) & ~(size_t)255;
        return p;
    };
    u16* xb = (u16*)alloc((size_t)NN * 256 * 2);
    u16* WbT = (u16*)alloc((size_t)768 * 256 * 2);
    u16* WoT = (u16*)alloc((size_t)256 * 512 * 2);
    u16* Qb = (u16*)alloc((size_t)NN * 256 * 2);
    u16* Kb = (u16*)alloc((size_t)NN * 256 * 2);
    u8* Vf8 = (u8*)alloc((size_t)NN * 256);
    u16* msg = Qb;  // alias: attn reads Q[node] fully into regs before writing msg[node]
    int* cnt = (int*)alloc((size_t)NN * 4);
    int* esrc = (int*)alloc((size_t)NN * BUCKET * 4);
    // total workspace ~ 232 MB

    hipMemsetAsync(cnt, 0, (size_t)NN * 4, stream);

    cvt_x_kernel<<<25000, 256, 0, stream>>>(x, xb, NN * 256 / 4);
    transpose_bf16_kernel<<<(256 * 768 + 255) / 256, 256, 0, stream>>>(W_qkv, WbT, 256, 768);
    transpose_bf16_kernel<<<(512 * 256 + 255) / 256, 256, 0, stream>>>(W_out, WoT, 512, 256);

    edge_bucket_kernel<<<EE / 256, 256, 0, stream>>>(src, dst, cnt, esrc);

    // QKV = xb @ W_qkv + b_qkv  -> Q,K bf16 + V fp8
    gemm_bt_kernel<1><<<782 * 6, 256, 0, stream>>>(xb, xb, 256, WbT, b_qkv, NN, 768, 256, 6,
                                                   nullptr, Qb, Kb, Vf8);

    attn_kernel<<<NN / 4, 256, 0, stream>>>(Qb, Kb, Vf8, cnt, esrc, msg);

    // out = [xb | msg] @ W_out + b_out  (fp32 out)
    gemm_bt_kernel<0><<<782 * 2, 256, 0, stream>>>(xb, msg, 256, WoT, b_out, NN, 256, 512, 2,
                                                   out, nullptr, nullptr, nullptr);
}